// Round 3
// baseline (118.818 us; speedup 1.0000x reference)
//
#include <hip/hip_runtime.h>
#include <math.h>

// Mecanum dynamics: per-row elementwise op, memory-bound (120 MB / launch).
// 2 rows per thread -> all global traffic is float4/float2 (16B/8B per lane),
// fully coalesced. Roofline ~19 us at 6.3 TB/s achievable HBM BW.

__device__ __forceinline__ void mecanum_row(
    float theta, float vx, float vy, float w,
    float u0, float u1, float u2,
    float& a0, float& a1, float& a2)
{
    // ---- compile-time constants (double math, cast to f32, matching numpy) ----
    constexpr double Gd   = 13.7;
    constexpr double LXd  = 0.129907;
    constexpr double LYd  = 0.095724;
    constexpr double Rd   = 3.0 * 0.0254;            // 0.0762
    constexpr double Kd   = LXd + LYd;               // 0.225631
    constexpr double MASSd = 12.0;
    constexpr double MOId = 12.0 * (12.0 * 0.0254) * (12.0 * 0.0254) / 6.0;

    const float Gf   = (float)Gd;
    const float invR = (float)(1.0 / Rd);            // LOCAL_TO_WHEEL_ROT +-1/R entries
    const float KoR  = (float)(Kd / Rd);             // +-(LX+LY)/R entries
    // pinv(local_to_wheel) closed form: MtM = diag(4,4,4k^2)
    //   row0 = [1,1,1,1]/4 ; row1 = [-1,1,1,-1]/4 ; row2 = [-1,1,-1,1]/(4k)
    const float s01  = (float)(0.25 / Rd / MASSd);   // rows 0,1 of WHEEL_TORQUE_TO_LOCAL_ACCEL
    const float s2   = (float)(1.0 / (4.0 * Kd) / Rd / MOId); // row 2

    float sn, cs;
    sincosf(theta, &sn, &cs);
    // A = rot(-theta): local_vel = A @ v
    const float lv0 = cs * vx + sn * vy;
    const float lv1 = cs * vy - sn * vx;
    // lv2 = w

    // sign patterns shared by local_to_wheel cols 1,2 and CTRL_TO_MOTOR cols 1,2
    const float bw[4] = { -1.f, 1.f,  1.f, -1.f };
    const float fw[4] = { -1.f, 1.f, -1.f,  1.f };

    const float wvc0 = invR * lv0;
    const float wvc1 = invR * lv1;
    const float wvc2 = KoR * w;

    float wt_sum = 0.f, wt_b = 0.f, wt_f = 0.f;
#pragma unroll
    for (int i = 0; i < 4; ++i) {
        const float wv = wvc0 + bw[i] * wvc1 + fw[i] * wvc2;
        const float md = u0 + bw[i] * u1 + fw[i] * u2;
        const float ss = wv / sqrtf(wv * wv + 0.01f);           // softsign, eps=0.01
        const float wt = (md * 0.193f - (wv * Gf) * 0.000304f - ss * 0.00317f) * Gf;
        wt_sum += wt;
        wt_b   += bw[i] * wt;
        wt_f   += fw[i] * wt;
    }

    const float la0 = wt_sum * s01;
    const float la1 = wt_b   * s01;
    const float la2 = wt_f   * s2;

    // absolute_accel = A^T @ local_accel
    a0 = cs * la0 - sn * la1;
    a1 = sn * la0 + cs * la1;
    a2 = la2;
}

__global__ __launch_bounds__(256) void mecanum_kernel(
    const float* __restrict__ state,
    const float* __restrict__ ctrl,
    float* __restrict__ out,
    int npairs)
{
    const int tid = blockIdx.x * blockDim.x + threadIdx.x;
    if (tid >= npairs) return;

    const float4* __restrict__ s4 = (const float4*)state;
    const float2* __restrict__ c2 = (const float2*)ctrl;
    float4* __restrict__ o4 = (float4*)out;

    const int base = 3 * tid;
    // two rows of state: 12 floats = 3 x float4
    const float4 sa = s4[base + 0];
    const float4 sb = s4[base + 1];
    const float4 sc = s4[base + 2];
    // two rows of ctrl: 6 floats = 3 x float2
    const float2 ca = c2[base + 0];
    const float2 cb = c2[base + 1];
    const float2 cc = c2[base + 2];

    // row 0: state = [sa.x sa.y sa.z sa.w sb.x sb.y], ctrl = [ca.x ca.y cb.x]
    float a00, a01, a02;
    mecanum_row(sa.z, sa.w, sb.x, sb.y, ca.x, ca.y, cb.x, a00, a01, a02);
    // row 1: state = [sb.z sb.w sc.x sc.y sc.z sc.w], ctrl = [cb.y cc.x cc.y]
    float a10, a11, a12;
    mecanum_row(sc.x, sc.y, sc.z, sc.w, cb.y, cc.x, cc.y, a10, a11, a12);

    // out rows: [vel(3), accel(3)] each -> 12 floats = 3 x float4
    float4 o0 = { sa.w, sb.x, sb.y, a00 };
    float4 o1 = { a01, a02, sc.y, sc.z };
    float4 o2 = { sc.w, a10, a11, a12 };
    o4[base + 0] = o0;
    o4[base + 1] = o1;
    o4[base + 2] = o2;
}

extern "C" void kernel_launch(void* const* d_in, const int* in_sizes, int n_in,
                              void* d_out, int out_size, void* d_ws, size_t ws_size,
                              hipStream_t stream) {
    // d_in[0] = t (unused, 1 elem), d_in[1] = state (B*6 f32), d_in[2] = control_duty (B*3 f32)
    const float* state = (const float*)d_in[1];
    const float* ctrl  = (const float*)d_in[2];
    float* out = (float*)d_out;

    const int B = in_sizes[1] / 6;          // 2,000,000
    const int npairs = B / 2;               // B is even
    const int block = 256;
    const int grid = (npairs + block - 1) / block;
    mecanum_kernel<<<grid, block, 0, stream>>>(state, ctrl, out, npairs);
}